// Round 2
// 547.749 us; speedup vs baseline: 1.0818x; 1.0818x over previous
//
#include <hip/hip_runtime.h>
#include <math.h>

#define Bb 128
#define Hh 4
#define Nn 8192
#define Dd 64

constexpr float BETA = 10.0f;
constexpr float EPSV = 1e-8f;

typedef float f32x4 __attribute__((ext_vector_type(4)));  // for nontemporal ops

// d_out layout (flat float32, reference return order):
constexpr long long OFF_RC = 0;                              // read_combined (B,D)
constexpr long long OFF_RW = (long long)Bb * Dd;             // r_w (B,H,N)
constexpr long long OFF_NM = OFF_RW + (long long)Bb*Hh*Nn;   // new_memory (B,N,D)
constexpr long long OFF_WW = OFF_NM + (long long)Bb*Nn*Dd;   // w_w (B,H,N)

// workspace layout:
//   ws_idx : int  [8192]                (compact top-8 idx lists for K3)
//   ws_wt  : float[8192]
//   cand_v : float[1024*256]            (per (b,head8,chunk) top-8 values)
//   cand_i : int  [1024*256]            (matching global n indices)

// ---------------------------------------------------------------------------
// K1: stream memory once. Per row: norm + 8 key dots (4 read + 4 write heads).
// Writes new_memory = 4*memory, zeros the r_w/w_w output rows for this chunk,
// and reduces its 256 sims per head to a per-chunk top-8 candidate list
// (hierarchical top-k: the global top-8 is always contained in the union of
// per-chunk top-8s, tie-break by lower index preserved at both levels).
// ---------------------------------------------------------------------------
__global__ __launch_bounds__(256) void k1_sims(
    const float* __restrict__ mem, const float* __restrict__ rkeys,
    const float* __restrict__ wkeys, float* __restrict__ out,
    float* __restrict__ cand_v, int* __restrict__ cand_i)
{
  __shared__ __align__(16) float keys[8 * 64];   // heads 0-3 read, 4-7 write
  __shared__ float knorm[8];
  __shared__ __align__(16) float sims[8][256];
  const int b = blockIdx.x >> 5;     // 32 chunks per batch
  const int c = blockIdx.x & 31;
  const int t = threadIdx.x;

  keys[t]       = rkeys[b * 256 + t];
  keys[256 + t] = wkeys[b * 256 + t];
  __syncthreads();
  if (t < 8) {
    float s = 0.f;
    for (int d = 0; d < 64; ++d) { float k = keys[t * 64 + d]; s += k * k; }
    knorm[t] = fmaxf(sqrtf(s), EPSV);
  }
  __syncthreads();

  const int g = t >> 4, q = t & 15;          // group (row), lane-in-group
  const float4* kvec = (const float4*)keys;  // kvec[h*16 + q]
  const int base = c * 256;

  for (int it = 0; it < 16; ++it) {
    const int n = base + it * 16 + g;
    const long long rowoff = ((long long)b * Nn + n) * Dd;
    f32x4 v = __builtin_nontemporal_load(((const f32x4*)(mem + rowoff)) + q);
    float acc[9];
    acc[8] = v.x*v.x + v.y*v.y + v.z*v.z + v.w*v.w;   // norm^2 partial
#pragma unroll
    for (int h = 0; h < 8; ++h) {
      float4 k4 = kvec[h * 16 + q];
      acc[h] = v.x*k4.x + v.y*k4.y + v.z*k4.z + v.w*k4.w;
    }
#pragma unroll
    for (int off = 1; off < 16; off <<= 1) {
#pragma unroll
      for (int j = 0; j < 9; ++j) acc[j] += __shfl_xor(acc[j], off, 64);
    }
    // new_memory = 4 * memory (bulk case; K3 fixes the <=32 written rows)
    f32x4 nm;
    nm.x = 4.f*v.x; nm.y = 4.f*v.y; nm.z = 4.f*v.z; nm.w = 4.f*v.w;
    __builtin_nontemporal_store(nm, ((f32x4*)(out + OFF_NM + rowoff)) + q);
    if (q < 8) {
      float m_norm = fmaxf(sqrtf(acc[8]), EPSV);
      sims[q][it * 16 + g] = BETA * acc[q] / (knorm[q] * m_norm + EPSV);
    }
  }

  // zero this chunk's segment of all 8 output weight rows (K2 scatters later)
  {
    const int zh = t >> 5, zq = t & 31;       // 8 heads x 32 lanes x 2 float4
    long long zo = (zh < 4) ? (OFF_RW + (long long)(b*4+zh) * Nn)
                            : (OFF_WW + (long long)(b*4+zh-4) * Nn);
    float4 z = make_float4(0.f, 0.f, 0.f, 0.f);
    float4* zp = (float4*)(out + zo + base);
    zp[zq] = z; zp[zq + 32] = z;
  }
  __syncthreads();

  // per-chunk top-8 per head: wave w handles heads 2w, 2w+1, no barriers.
  const int wid = t >> 6, lane = t & 63;
#pragma unroll
  for (int hh = 0; hh < 2; ++hh) {
    const int h = wid * 2 + hh;
    float4 sv = ((const float4*)(&sims[h][0]))[lane];  // sims[h][lane*4+j]
    float v0 = sv.x, v1 = sv.y, v2 = sv.z, v3 = sv.w;
    const int nb = base + lane * 4;
    const long long cofs = ((long long)(b * 8 + h) * 32 + c) * 8;
#pragma unroll
    for (int k = 0; k < 8; ++k) {
      // local best of 4 (strict > keeps lowest index on ties: idx grows with j)
      float bv = v0; int bj = 0;
      if (v1 > bv) { bv = v1; bj = 1; }
      if (v2 > bv) { bv = v2; bj = 2; }
      if (v3 > bv) { bv = v3; bj = 3; }
      int bi = nb + bj;
#pragma unroll
      for (int off = 1; off < 64; off <<= 1) {
        float ov = __shfl_xor(bv, off, 64);
        int   oi = __shfl_xor(bi, off, 64);
        if (ov > bv || (ov == bv && oi < bi)) { bv = ov; bi = oi; }
      }
      if (lane == k) { cand_v[cofs + k] = bv; cand_i[cofs + k] = bi; }
      // invalidate the extracted slot (owner lane only; others no-op)
      int r = bi - nb;
      if (r == 0) v0 = -3.0e38f;
      else if (r == 1) v1 = -3.0e38f;
      else if (r == 2) v2 = -3.0e38f;
      else if (r == 3) v3 = -3.0e38f;
    }
  }
}

// ---------------------------------------------------------------------------
// K2: merge. One wave per (b, head8) row: reduce 32 chunks x 8 candidates
// (2 MB total, L2-resident) to the global top-8, softmax over the 8, scatter
// weights into the pre-zeroed output row, emit compact lists for K3.
// No __syncthreads at all.
// ---------------------------------------------------------------------------
__global__ __launch_bounds__(64) void k2_merge(
    const float* __restrict__ cand_v, const int* __restrict__ cand_i,
    float* __restrict__ out, int* __restrict__ ws_idx, float* __restrict__ ws_wt)
{
  const int blk = blockIdx.x;        // [0,1024): b*8 + head8
  const int b = blk >> 3, h8 = blk & 7;
  const int lane = threadIdx.x;
  const long long cbase = (long long)blk * 256;
  float4 cv4 = ((const float4*)(cand_v + cbase))[lane];
  int4   ci4 = ((const int4*)(cand_i + cbase))[lane];
  float v0 = cv4.x, v1 = cv4.y, v2 = cv4.z, v3 = cv4.w;
  int   i0 = ci4.x, i1 = ci4.y, i2 = ci4.z, i3 = ci4.w;

  float cv[8]; int ci[8];            // static-indexed only (unrolled)
#pragma unroll
  for (int k = 0; k < 8; ++k) {
    float bv = v0; int bi = i0;
    if (v1 > bv || (v1 == bv && i1 < bi)) { bv = v1; bi = i1; }
    if (v2 > bv || (v2 == bv && i2 < bi)) { bv = v2; bi = i2; }
    if (v3 > bv || (v3 == bv && i3 < bi)) { bv = v3; bi = i3; }
#pragma unroll
    for (int off = 1; off < 64; off <<= 1) {
      float ov = __shfl_xor(bv, off, 64);
      int   oi = __shfl_xor(bi, off, 64);
      if (ov > bv || (ov == bv && oi < bi)) { bv = ov; bi = oi; }
    }
    cv[k] = bv; ci[k] = bi;
    // invalidate by index (indices are globally unique across candidates)
    if (i0 == bi) v0 = -3.0e38f;
    if (i1 == bi) v1 = -3.0e38f;
    if (i2 == bi) v2 = -3.0e38f;
    if (i3 == bi) v3 = -3.0e38f;
  }

  // softmax over the 8 selected (others are exactly 0 in fp32, matching ref)
  float m = cv[0], den = 0.f, e[8];
#pragma unroll
  for (int k = 0; k < 8; ++k) { e[k] = expf(cv[k] - m); den += e[k]; }

  float* row = out + ((h8 < 4) ? (OFF_RW + (long long)(b*4+h8) * Nn)
                               : (OFF_WW + (long long)(b*4+h8-4) * Nn));
  const int wsofs = (h8 < 4) ? (b*32 + h8*8) : (4096 + b*32 + (h8-4)*8);
#pragma unroll
  for (int k = 0; k < 8; ++k) {
    if (lane == k) {
      float w = e[k] / den;
      row[ci[k]]       = w;
      ws_idx[wsofs + k] = ci[k];
      ws_wt[wsofs + k]  = w;
    }
  }
}

// ---------------------------------------------------------------------------
// K3: per batch b, 256 threads = 4 waves x 64 d-lanes.
//  - read_combined: each wave accumulates 8 of the 32 read entries, LDS-reduce.
//  - write rows: wave g owns entries e === g (mod 4); first-occurrence owner
//    merges duplicates (owners have distinct n -> parallel-safe). Duplicate
//    bookkeeping lives in LDS (broadcast reads, no scratch spill).
// ---------------------------------------------------------------------------
__global__ __launch_bounds__(256) void k3_apply(
    const float* __restrict__ mem, const float* __restrict__ wvals,
    const float* __restrict__ erase, const int* __restrict__ ws_idx,
    const float* __restrict__ ws_wt, float* __restrict__ out)
{
  const int b = blockIdx.x;
  const int t = threadIdx.x;
  const int d = t & 63, g = t >> 6;        // g == wave id
  __shared__ float part[4][64];
  __shared__ int   snn[32];
  __shared__ float swt[32];

  if (t < 32) { snn[t] = ws_idx[4096 + b*32 + t]; swt[t] = ws_wt[4096 + b*32 + t]; }

  float acc = 0.f;
#pragma unroll
  for (int e8 = 0; e8 < 8; ++e8) {
    const int e = g * 8 + e8;
    const int n = ws_idx[b*32 + e];
    const float w = ws_wt[b*32 + e];
    acc += w * mem[((long long)b * Nn + n) * Dd + d];
  }
  part[g][d] = acc;
  __syncthreads();
  if (g == 0)
    out[OFF_RC + b*64 + d] = 0.25f * (part[0][d] + part[1][d] + part[2][d] + part[3][d]);

  for (int ee = 0; ee < 8; ++ee) {
    const int e = ee * 4 + g;                // wave-uniform
    const int n = snn[e];
    bool first = true;
    for (int j = 0; j < e; ++j) if (snn[j] == n) first = false;
    if (first) {                             // uniform within the wave
      float E = 0.f, A = 0.f;
      for (int j = e; j < 32; ++j) if (snn[j] == n) {
        const int h = j >> 3;
        E += swt[j] * erase[((long long)b*4 + h) * 64 + d];
        A += swt[j] * wvals[((long long)b*4 + h) * 64 + d];
      }
      const float m = mem[((long long)b * Nn + n) * Dd + d];
      out[OFF_NM + ((long long)b * Nn + n) * Dd + d] = m * (4.f - E) + A;
    }
  }
}

extern "C" void kernel_launch(void* const* d_in, const int* in_sizes, int n_in,
                              void* d_out, int out_size, void* d_ws, size_t ws_size,
                              hipStream_t stream) {
  (void)in_sizes; (void)n_in; (void)out_size; (void)ws_size;
  const float* mem   = (const float*)d_in[0];
  const float* rkeys = (const float*)d_in[1];
  const float* wkeys = (const float*)d_in[2];
  const float* wvals = (const float*)d_in[3];
  const float* erase = (const float*)d_in[4];
  float* out = (float*)d_out;
  int*   ws_idx = (int*)d_ws;
  float* ws_wt  = (float*)((char*)d_ws + 8192 * sizeof(int));
  float* cand_v = (float*)((char*)d_ws + 16384 * sizeof(int));
  int*   cand_i = (int*)((char*)d_ws + 16384 * sizeof(int) + (long long)1024*256*sizeof(float));

  hipLaunchKernelGGL(k1_sims, dim3(Bb * 32), dim3(256), 0, stream,
                     mem, rkeys, wkeys, out, cand_v, cand_i);
  hipLaunchKernelGGL(k2_merge, dim3(1024), dim3(64), 0, stream,
                     cand_v, cand_i, out, ws_idx, ws_wt);
  hipLaunchKernelGGL(k3_apply, dim3(Bb), dim3(256), 0, stream,
                     mem, wvals, erase, ws_idx, ws_wt, out);
}